// Round 2
// baseline (434.434 us; speedup 1.0000x reference)
//
#include <hip/hip_runtime.h>
#include <cstdint>
#include <cmath>

// ---------------------------------------------------------------------------
// WignerD: out[b] = block-diag over IRREPS_L=[0]*32+[1]*16+[2]*8+[3]*8+[4]*4
// of Dl(b) = Zrot(l,alpha) @ A[l] @ Zrot(l,beta) @ AINV[l] @ Zrot(l,gamma).
// DIM = 212, B = 2048, out = (B,212,212) fp32 = 368 MB (97.6% zeros).
//
// R2: fused zero-fill. The rocclr fillBufferAligned memset wrote 1.47 GB
// (4x amplification) in 267 us. Instead each block zeroes its own slice with
// float4 stores, then overwrites the 1092 diagonal entries (ordered by the
// existing __syncthreads()). Exactly 368 MB of HBM writes -> ~58 us floor.
//
// A[l] (Wigner of the fixed rotation _RX) is recomputed on-device every launch
// by a tiny setup kernel: least-squares fit of real-SH values at 48
// deterministic points (exact since SH rotation is an exact linear map).
// A is orthogonal => AINV = A^T.
// ---------------------------------------------------------------------------

#define WDIM 212
#define NBLK 165    // sum over l of (2l+1)^2
#define NWRITE 1092 // sum over irreps of (2l+1)^2
#define SLICE (WDIM * WDIM)      // 44944 floats
#define SLICE4 (SLICE / 4)       // 11236 float4s

__device__ __constant__ int c_moff[5] = {0, 1, 10, 35, 84};

struct TabM { unsigned char l[NBLK], i[NBLK], j[NBLK]; };
constexpr TabM make_tabM() {
  TabM t{};
  int idx = 0;
  for (int l = 0; l < 5; l++) {
    int n = 2 * l + 1;
    for (int i = 0; i < n; i++)
      for (int j = 0; j < n; j++) {
        t.l[idx] = (unsigned char)l;
        t.i[idx] = (unsigned char)i;
        t.j[idx] = (unsigned char)j;
        idx++;
      }
  }
  return t;
}
__device__ __constant__ TabM c_tabM = make_tabM();

struct TabW { unsigned short off[NWRITE]; unsigned char l[NWRITE], i[NWRITE], j[NWRITE]; };
constexpr TabW make_tabW() {
  TabW t{};
  const int cnt[5] = {32, 16, 8, 8, 4};
  const int start[5] = {0, 32, 80, 120, 176};
  int idx = 0;
  for (int l = 0; l < 5; l++) {
    int n = 2 * l + 1;
    for (int c = 0; c < cnt[l]; c++) {
      int off = start[l] + c * n;
      for (int i = 0; i < n; i++)
        for (int j = 0; j < n; j++) {
          t.off[idx] = (unsigned short)off;
          t.l[idx] = (unsigned char)l;
          t.i[idx] = (unsigned char)i;
          t.j[idx] = (unsigned char)j;
          idx++;
        }
    }
  }
  return t;
}
__device__ __constant__ TabW c_tabW = make_tabW();

// A[165] then AINV[165], written by setup kernel each launch.
__device__ float g_ws[330];

// splitmix64 -> double in [-1,1)
__device__ inline double rnd_double(uint64_t x) {
  x += 0x9E3779B97F4A7C15ull;
  x = (x ^ (x >> 30)) * 0xBF58476D1CE4E5B9ull;
  x = (x ^ (x >> 27)) * 0x94D049BB133111EBull;
  x ^= x >> 31;
  return (double)(x >> 11) * (1.0 / 4503599627370496.0) - 1.0;
}

// Real spherical harmonics, same convention as the reference (CS phase inside P).
__device__ void eval_real_sh(int l, const double p[3], double* outv) {
  const double x = p[0], y = p[1], z = p[2];
  const double phi = atan2(y, x);
  double P[5];
  for (int m = 0; m <= l; m++) {
    double pmm = 1.0;
    if (m > 0) {
      double somx2 = sqrt(fmax(1.0 - z * z, 0.0));
      double fct = 1.0;
      for (int k = 0; k < m; k++) { pmm = -pmm * fct * somx2; fct += 2.0; }
    }
    if (l == m) { P[m] = pmm; continue; }
    double pmmp1 = z * (2 * m + 1) * pmm;
    if (l == m + 1) { P[m] = pmmp1; continue; }
    for (int ll = m + 2; ll <= l; ll++) {
      double pll = ((2 * ll - 1) * z * pmmp1 - (ll + m - 1) * pmm) / (double)(ll - m);
      pmm = pmmp1;
      pmmp1 = pll;
    }
    P[m] = pmmp1;
  }
  const double fact[9] = {1, 1, 2, 6, 24, 120, 720, 5040, 40320};
  const double four_pi = 4.0 * 3.14159265358979323846;
  for (int m = -l; m <= l; m++) {
    int am = m < 0 ? -m : m;
    double N = sqrt((2 * l + 1) / four_pi * fact[l - am] / fact[l + am]);
    double v;
    if (m == 0) v = N * P[0];
    else if (m > 0) v = sqrt(2.0) * N * P[am] * cos(m * phi);
    else v = sqrt(2.0) * N * P[am] * sin(am * phi);
    outv[m + l] = v;
  }
}

// One wave per l (5 waves). Least-squares A from 48 sample points, then
// AINV = A^T (A is orthogonal). Doubles throughout; store float to g_ws.
__global__ __launch_bounds__(320) void wigner_setup() {
  const int l = threadIdx.x >> 6;
  const int lane = threadIdx.x & 63;
  const int n = 2 * l + 1;

  __shared__ double Y[5][48][9];
  __shared__ double Yr[5][48][9];
  __shared__ double G[5][9][18]; // [G | C] augmented
  __shared__ double F[5][9];

  if (lane < 48) {
    uint64_t base = ((uint64_t)l * 1024u + (uint64_t)lane) * 4u + 1u;
    double p[3];
    double nrm2 = 0.0;
    for (int c = 0; c < 3; c++) { p[c] = rnd_double(base + (uint64_t)c); nrm2 += p[c] * p[c]; }
    if (nrm2 < 1e-12) { p[0] = 1.0; p[1] = 0.5; p[2] = 0.25; nrm2 = 1.3125; }
    double invn = 1.0 / sqrt(nrm2);
    p[0] *= invn; p[1] *= invn; p[2] *= invn;
    double q[3] = { p[0], p[2], -p[1] }; // _RX applied: (x,y,z) -> (x,z,-y)
    eval_real_sh(l, p, &Y[l][lane][0]);
    eval_real_sh(l, q, &Yr[l][lane][0]);
  }
  __syncthreads();

  // Normal equations: G = Y^T Y (pad to I), C = Y^T Yr (pad 0)
  for (int e = lane; e < 162; e += 64) {
    int r = e / 18, c = e % 18;
    double v;
    if (c < 9) {
      if (r < n && c < n) {
        v = 0.0;
        for (int s = 0; s < 48; s++) v += Y[l][s][r] * Y[l][s][c];
      } else v = (r == c) ? 1.0 : 0.0;
    } else {
      int cc = c - 9;
      if (r < n && cc < n) {
        v = 0.0;
        for (int s = 0; s < 48; s++) v += Y[l][s][r] * Yr[l][s][cc];
      } else v = 0.0;
    }
    G[l][r][c] = v;
  }
  __syncthreads();

  // Gauss-Jordan (G is SPD + identity padding: no pivoting needed)
  for (int k = 0; k < 9; k++) {
    double ipiv = 1.0 / G[l][k][k];
    if (lane < 18) G[l][k][lane] *= ipiv;
    __syncthreads();
    if (lane < 9) F[l][lane] = G[l][lane][k];
    __syncthreads();
    for (int e = lane; e < 162; e += 64) {
      int r = e / 18, c = e % 18;
      if (r != k) G[l][r][c] -= F[l][r] * G[l][k][c];
    }
    __syncthreads();
  }

  // X = right half solves Yx@X ~= Yrx ; A = X^T ; AINV = A^T = X
  for (int e = lane; e < n * n; e += 64) {
    int i = e / n, j = e % n;
    g_ws[c_moff[l] + e]       = (float)G[l][j][9 + i]; // A[i][j]
    g_ws[165 + c_moff[l] + e] = (float)G[l][i][9 + j]; // AINV[i][j]
  }
}

// One block per batch element. Zero-fills its own slice (float4 streaming),
// then writes the 1092 diagonal-block entries.
__global__ __launch_bounds__(256) void wigner_main(const float* __restrict__ alpha,
                                                   const float* __restrict__ beta,
                                                   const float* __restrict__ gamma,
                                                   float* __restrict__ out) {
  const int b = blockIdx.x;
  const int tid = threadIdx.x;
  const float a = alpha[b];
  const float be = beta[b];
  const float g = gamma[b];

  __shared__ float sA[330]; // A then AINV
  __shared__ float sT[NBLK];
  __shared__ float sM[NBLK];

  // ---- phase 0: zero-fill this batch's 212x212 slice with float4 stores ----
  // slice base: b*44944 floats = b*179776 bytes (16B-aligned since 179776%16==0)
  float4* __restrict__ oz = (float4*)(out + (size_t)b * SLICE);
  const float4 z4 = make_float4(0.f, 0.f, 0.f, 0.f);
  #pragma unroll 4
  for (int e = tid; e < SLICE4; e += 256) oz[e] = z4;

  // ---- stage constants while stores are in flight ----
  for (int e = tid; e < 330; e += 256) sA[e] = g_ws[e];
  __syncthreads();

  // T = Zbeta @ AINV  (Z row i: cos(m_i b) at i, -sin(m_i b) at n-1-i)
  for (int e = tid; e < NBLK; e += 256) {
    int l = c_tabM.l[e], i = c_tabM.i[e], j = c_tabM.j[e];
    int n = 2 * l + 1, moff = c_moff[l];
    int i2 = n - 1 - i;
    float mi = (float)(i - l);
    float sb, cb;
    __sincosf(mi * be, &sb, &cb);
    sT[e] = cb * sA[165 + moff + i * n + j] - sb * sA[165 + moff + i2 * n + j];
  }
  __syncthreads();

  // M = A @ T
  for (int e = tid; e < NBLK; e += 256) {
    int l = c_tabM.l[e], i = c_tabM.i[e], j = c_tabM.j[e];
    int n = 2 * l + 1, moff = c_moff[l];
    float acc = 0.f;
    for (int k = 0; k < n; k++) acc += sA[moff + i * n + k] * sT[moff + k * n + j];
    sM[e] = acc;
  }
  __syncthreads(); // also orders the phase-0 zero stores before the diag stores

  // D[i,j] = cos(mi*a)*(M[i,j]cg + M[i,j']sg) - sin(mi*a)*(M[i',j]cg + M[i',j']sg)
  const size_t obase = (size_t)b * SLICE;
  for (int t = tid; t < NWRITE; t += 256) {
    int l = c_tabW.l[t], i = c_tabW.i[t], j = c_tabW.j[t];
    int off = c_tabW.off[t];
    int n = 2 * l + 1, moff = c_moff[l];
    int i2 = n - 1 - i, j2 = n - 1 - j;
    float mi = (float)(i - l), mj = (float)(j - l);
    float sa, ca, sg, cg;
    __sincosf(mi * a, &sa, &ca);
    __sincosf(mj * g, &sg, &cg);
    float r0 = sM[moff + i * n + j] * cg + sM[moff + i * n + j2] * sg;
    float r1 = sM[moff + i2 * n + j] * cg + sM[moff + i2 * n + j2] * sg;
    out[obase + (size_t)(off + i) * WDIM + (off + j)] = ca * r0 - sa * r1;
  }
}

extern "C" void kernel_launch(void* const* d_in, const int* in_sizes, int n_in,
                              void* d_out, int out_size, void* d_ws, size_t ws_size,
                              hipStream_t stream) {
  const float* alpha = (const float*)d_in[0];
  const float* beta  = (const float*)d_in[1];
  const float* gamma = (const float*)d_in[2];
  float* out = (float*)d_out;
  const int B = in_sizes[0];

  // Recompute A/AINV constants (identical work every call; graph-safe).
  wigner_setup<<<1, 320, 0, stream>>>();
  // Fused: zero-fill + diagonal-block writes, exactly 368 MB of HBM writes.
  wigner_main<<<B, 256, 0, stream>>>(alpha, beta, gamma, out);
}

// Round 4
// 397.041 us; speedup vs baseline: 1.0942x; 1.0942x over previous
//
#include <hip/hip_runtime.h>
#include <cstdint>
#include <cmath>

// ---------------------------------------------------------------------------
// WignerD: out[b] = block-diag over IRREPS_L=[0]*32+[1]*16+[2]*8+[3]*8+[4]*4
// of Dl(b) = Zrot(l,alpha) @ A[l] @ Zrot(l,beta) @ AINV[l] @ Zrot(l,gamma).
// DIM = 212, B = 2048, out = (B,212,212) fp32 = 368 MB (97.6% zeros).
//
// Timing decomposition (R1/R2 counters): harness 0xAA re-poison fill = 267 us
// (unavoidable, stream-serialized); our graph was ~165 us of which ~70 us was
// the setup kernel's FP64 atan2/sin/cos software sequences.
// R4 (= R3 with compile fix): (a) setup uses the Chebyshev recurrence for
// cos/sin(m*phi) -> no transcendental calls except sqrt; (b) main writes each
// output byte exactly once: nonzeros staged in LDS, then one float4 streaming
// pass over the slice using a native ext_vector_type for nontemporal stores.
// ---------------------------------------------------------------------------

#define WDIM 212
#define NBLK 165    // sum over l of (2l+1)^2
#define NWRITE 1092 // sum over irreps of (2l+1)^2
#define SLICE (WDIM * WDIM)      // 44944 floats
#define SLICE4 (SLICE / 4)       // 11236 float4s; 11236 = 212*53

typedef float vfloat4 __attribute__((ext_vector_type(4)));

__device__ __constant__ int c_moff[5] = {0, 1, 10, 35, 84};

struct TabM { unsigned char l[NBLK], i[NBLK], j[NBLK]; };
constexpr TabM make_tabM() {
  TabM t{};
  int idx = 0;
  for (int l = 0; l < 5; l++) {
    int n = 2 * l + 1;
    for (int i = 0; i < n; i++)
      for (int j = 0; j < n; j++) {
        t.l[idx] = (unsigned char)l;
        t.i[idx] = (unsigned char)i;
        t.j[idx] = (unsigned char)j;
        idx++;
      }
  }
  return t;
}
__device__ __constant__ TabM c_tabM = make_tabM();

// Nonzero-entry table in sD order: irrep-major, row-major, col-major.
struct TabW { unsigned char l[NWRITE], i[NWRITE], j[NWRITE]; };
constexpr TabW make_tabW() {
  TabW t{};
  const int cnt[5] = {32, 16, 8, 8, 4};
  int idx = 0;
  for (int l = 0; l < 5; l++) {
    int n = 2 * l + 1;
    for (int c = 0; c < cnt[l]; c++)
      for (int i = 0; i < n; i++)
        for (int j = 0; j < n; j++) {
          t.l[idx] = (unsigned char)l;
          t.i[idx] = (unsigned char)i;
          t.j[idx] = (unsigned char)j;
          idx++;
        }
  }
  return t;
}
__device__ __constant__ TabW c_tabW = make_tabW();

// Per-global-row packed info: bits[0:12)=dstart into sD, [12:20)=block col
// offset, [20:24)=n. sD order matches TabW order (rows contiguous).
struct RowTab { unsigned int v[WDIM]; };
constexpr RowTab make_rows() {
  RowTab t{};
  const int cnt[5] = {32, 16, 8, 8, 4};
  int row = 0, d = 0;
  for (int li = 0; li < 5; li++) {
    int n = 2 * li + 1;
    for (int c = 0; c < cnt[li]; c++) {
      int off = row;
      for (int i = 0; i < n; i++) {
        t.v[row] = (unsigned)(d | (off << 12) | (n << 20));
        d += n;
        row++;
      }
    }
  }
  return t;
}
__device__ __constant__ RowTab c_rows = make_rows();

// A[165] then AINV[165], written by setup kernel each launch.
__device__ float g_ws[330];

// splitmix64 -> double in [-1,1)
__device__ inline double rnd_double(uint64_t x) {
  x += 0x9E3779B97F4A7C15ull;
  x = (x ^ (x >> 30)) * 0xBF58476D1CE4E5B9ull;
  x = (x ^ (x >> 27)) * 0x94D049BB133111EBull;
  x ^= x >> 31;
  return (double)(x >> 11) * (1.0 / 4503599627370496.0) - 1.0;
}

// Real spherical harmonics (reference convention, CS phase inside P).
// No atan2/sin/cos: cos(m*phi), sin(m*phi) by angle-addition recurrence from
// (x/rho, y/rho). Only sqrt remains.
__device__ void eval_real_sh(int l, const double p[3], double* outv) {
  const double x = p[0], y = p[1], z = p[2];
  double rho2 = x * x + y * y;
  double cm[5], sm[5];
  cm[0] = 1.0; sm[0] = 0.0;
  {
    double c1, s1;
    if (rho2 > 1e-300) {
      double ir = 1.0 / sqrt(rho2);
      c1 = x * ir; s1 = y * ir;
    } else { c1 = 1.0; s1 = 0.0; }
    for (int m = 1; m <= l; m++) {
      cm[m] = cm[m - 1] * c1 - sm[m - 1] * s1;
      sm[m] = sm[m - 1] * c1 + cm[m - 1] * s1;
    }
  }
  double P[5];
  for (int m = 0; m <= l; m++) {
    double pmm = 1.0;
    if (m > 0) {
      double somx2 = sqrt(fmax(1.0 - z * z, 0.0));
      double fct = 1.0;
      for (int k = 0; k < m; k++) { pmm = -pmm * fct * somx2; fct += 2.0; }
    }
    if (l == m) { P[m] = pmm; continue; }
    double pmmp1 = z * (2 * m + 1) * pmm;
    if (l == m + 1) { P[m] = pmmp1; continue; }
    for (int ll = m + 2; ll <= l; ll++) {
      double pll = ((2 * ll - 1) * z * pmmp1 - (ll + m - 1) * pmm) / (double)(ll - m);
      pmm = pmmp1;
      pmmp1 = pll;
    }
    P[m] = pmmp1;
  }
  const double fact[9] = {1, 1, 2, 6, 24, 120, 720, 5040, 40320};
  const double four_pi = 4.0 * 3.14159265358979323846;
  for (int m = -l; m <= l; m++) {
    int am = m < 0 ? -m : m;
    double N = sqrt((2 * l + 1) / four_pi * fact[l - am] / fact[l + am]);
    double v;
    if (m == 0) v = N * P[0];
    else if (m > 0) v = sqrt(2.0) * N * P[am] * cm[am];
    else v = sqrt(2.0) * N * P[am] * sm[am];
    outv[m + l] = v;
  }
}

// One wave per l (5 waves). Least-squares A from 48 sample points, then
// AINV = A^T (A is orthogonal). Doubles throughout; store float to g_ws.
__global__ __launch_bounds__(320) void wigner_setup() {
  const int l = threadIdx.x >> 6;
  const int lane = threadIdx.x & 63;
  const int n = 2 * l + 1;

  __shared__ double Y[5][48][9];
  __shared__ double Yr[5][48][9];
  __shared__ double G[5][9][18]; // [G | C] augmented
  __shared__ double F[5][9];

  if (lane < 48) {
    uint64_t base = ((uint64_t)l * 1024u + (uint64_t)lane) * 4u + 1u;
    double p[3];
    double nrm2 = 0.0;
    for (int c = 0; c < 3; c++) { p[c] = rnd_double(base + (uint64_t)c); nrm2 += p[c] * p[c]; }
    if (nrm2 < 1e-12) { p[0] = 1.0; p[1] = 0.5; p[2] = 0.25; nrm2 = 1.3125; }
    double invn = 1.0 / sqrt(nrm2);
    p[0] *= invn; p[1] *= invn; p[2] *= invn;
    double q[3] = { p[0], p[2], -p[1] }; // _RX applied: (x,y,z) -> (x,z,-y)
    eval_real_sh(l, p, &Y[l][lane][0]);
    eval_real_sh(l, q, &Yr[l][lane][0]);
  }
  __syncthreads();

  // Normal equations: G = Y^T Y (pad to I), C = Y^T Yr (pad 0)
  for (int e = lane; e < 162; e += 64) {
    int r = e / 18, c = e % 18;
    double v;
    if (c < 9) {
      if (r < n && c < n) {
        v = 0.0;
        for (int s = 0; s < 48; s++) v += Y[l][s][r] * Y[l][s][c];
      } else v = (r == c) ? 1.0 : 0.0;
    } else {
      int cc = c - 9;
      if (r < n && cc < n) {
        v = 0.0;
        for (int s = 0; s < 48; s++) v += Y[l][s][r] * Yr[l][s][cc];
      } else v = 0.0;
    }
    G[l][r][c] = v;
  }
  __syncthreads();

  // Gauss-Jordan (G is SPD + identity padding: no pivoting needed)
  for (int k = 0; k < 9; k++) {
    double ipiv = 1.0 / G[l][k][k];
    if (lane < 18) G[l][k][lane] *= ipiv;
    __syncthreads();
    if (lane < 9) F[l][lane] = G[l][lane][k];
    __syncthreads();
    for (int e = lane; e < 162; e += 64) {
      int r = e / 18, c = e % 18;
      if (r != k) G[l][r][c] -= F[l][r] * G[l][k][c];
    }
    __syncthreads();
  }

  // X = right half solves Yx@X ~= Yrx ; A = X^T ; AINV = A^T = X
  for (int e = lane; e < n * n; e += 64) {
    int i = e / n, j = e % n;
    g_ws[c_moff[l] + e]       = (float)G[l][j][9 + i]; // A[i][j]
    g_ws[165 + c_moff[l] + e] = (float)G[l][i][9 + j]; // AINV[i][j]
  }
}

// One block per batch element. Stages all 1092 nonzeros in LDS, then writes
// the whole 212x212 slice in one float4 streaming pass (each byte once).
__global__ __launch_bounds__(256) void wigner_main(const float* __restrict__ alpha,
                                                   const float* __restrict__ beta,
                                                   const float* __restrict__ gamma,
                                                   float* __restrict__ out) {
  const int b = blockIdx.x;
  const int tid = threadIdx.x;
  const float a = alpha[b];
  const float be = beta[b];
  const float g = gamma[b];

  __shared__ float sA[330]; // A then AINV
  __shared__ float sT[NBLK];
  __shared__ float sM[NBLK];
  __shared__ float sD[NWRITE];
  __shared__ unsigned int sRow[WDIM];

  for (int e = tid; e < 330; e += 256) sA[e] = g_ws[e];
  if (tid < WDIM) sRow[tid] = c_rows.v[tid];
  __syncthreads();

  // T = Zbeta @ AINV  (Z row i: cos(m_i b) at i, -sin(m_i b) at n-1-i)
  for (int e = tid; e < NBLK; e += 256) {
    int l = c_tabM.l[e], i = c_tabM.i[e], j = c_tabM.j[e];
    int n = 2 * l + 1, moff = c_moff[l];
    int i2 = n - 1 - i;
    float mi = (float)(i - l);
    float sb, cb;
    __sincosf(mi * be, &sb, &cb);
    sT[e] = cb * sA[165 + moff + i * n + j] - sb * sA[165 + moff + i2 * n + j];
  }
  __syncthreads();

  // M = A @ T
  for (int e = tid; e < NBLK; e += 256) {
    int l = c_tabM.l[e], i = c_tabM.i[e], j = c_tabM.j[e];
    int n = 2 * l + 1, moff = c_moff[l];
    float acc = 0.f;
    for (int k = 0; k < n; k++) acc += sA[moff + i * n + k] * sT[moff + k * n + j];
    sM[e] = acc;
  }
  __syncthreads();

  // sD[t] = cos(mi*a)*(M[i,j]cg + M[i,j']sg) - sin(mi*a)*(M[i',j]cg + M[i',j']sg)
  for (int t = tid; t < NWRITE; t += 256) {
    int l = c_tabW.l[t], i = c_tabW.i[t], j = c_tabW.j[t];
    int n = 2 * l + 1, moff = c_moff[l];
    int i2 = n - 1 - i, j2 = n - 1 - j;
    float mi = (float)(i - l), mj = (float)(j - l);
    float sa, ca, sg, cg;
    __sincosf(mi * a, &sa, &ca);
    __sincosf(mj * g, &sg, &cg);
    float r0 = sM[moff + i * n + j] * cg + sM[moff + i * n + j2] * sg;
    float r1 = sM[moff + i2 * n + j] * cg + sM[moff + i2 * n + j2] * sg;
    sD[t] = ca * r0 - sa * r1;
  }
  __syncthreads();

  // Streaming pass: 11236 float4s, each byte written exactly once.
  vfloat4* __restrict__ oz = (vfloat4*)(out + (size_t)b * SLICE);
  #pragma unroll 2
  for (int e = tid; e < SLICE4; e += 256) {
    int r = e / 53;              // magic-mul division
    int c0 = (e - r * 53) * 4;   // starting global col of this float4
    unsigned info = sRow[r];
    int dstart = info & 0xFFF;
    int off = (info >> 12) & 0xFF;
    int n = (info >> 20) & 0xF;
    vfloat4 v = (vfloat4)(0.f);
    int i0 = c0 - off;
    #pragma unroll
    for (int q = 0; q < 4; q++) {
      int idx = i0 + q;
      if ((unsigned)idx < (unsigned)n) v[q] = sD[dstart + idx];
    }
    __builtin_nontemporal_store(v, oz + e);
  }
}

extern "C" void kernel_launch(void* const* d_in, const int* in_sizes, int n_in,
                              void* d_out, int out_size, void* d_ws, size_t ws_size,
                              hipStream_t stream) {
  const float* alpha = (const float*)d_in[0];
  const float* beta  = (const float*)d_in[1];
  const float* gamma = (const float*)d_in[2];
  float* out = (float*)d_out;
  const int B = in_sizes[0];

  // Recompute A/AINV constants (identical work every call; graph-safe).
  wigner_setup<<<1, 320, 0, stream>>>();
  // Single-pass: zeros + diagonal blocks, exactly 368 MB of HBM writes.
  wigner_main<<<B, 256, 0, stream>>>(alpha, beta, gamma, out);
}

// Round 5
// 380.845 us; speedup vs baseline: 1.1407x; 1.0425x over previous
//
#include <hip/hip_runtime.h>
#include <cstdint>
#include <cmath>

// ---------------------------------------------------------------------------
// WignerD: out[b] = block-diag over IRREPS_L=[0]*32+[1]*16+[2]*8+[3]*8+[4]*4
// of Dl(b) = Zrot(l,alpha) @ A[l] @ Zrot(l,beta) @ AINV[l] @ Zrot(l,gamma).
// DIM = 212, B = 2048, out = (B,212,212) fp32 = 368 MB (97.6% zeros).
//
// R5: (a) A/AINV computed at COMPILE TIME (constexpr least-squares fit of
// real-SH values at 48 deterministic points; Newton csqrt; Chebyshev
// cos/sin(m*phi) recurrence) -> __constant__ table, no setup kernel, the
// graph is a single 2048-block kernel. (b) plain float4 stores instead of
// nontemporal (the rocclr fill hits 6.3 TB/s with regular stores; NT was a
// suspect for main running ~2x over the 58 us write floor).
// Main writes each output byte exactly once: nonzeros staged in LDS, then one
// float4 streaming pass over the slice.
// ---------------------------------------------------------------------------

#define WDIM 212
#define NBLK 165    // sum over l of (2l+1)^2
#define NWRITE 1092 // sum over irreps of (2l+1)^2
#define SLICE (WDIM * WDIM)      // 44944 floats
#define SLICE4 (SLICE / 4)       // 11236 float4s; 11236 = 212*53

typedef float vfloat4 __attribute__((ext_vector_type(4)));

__device__ __constant__ int c_moff[5] = {0, 1, 10, 35, 84};

struct TabM { unsigned char l[NBLK], i[NBLK], j[NBLK]; };
constexpr TabM make_tabM() {
  TabM t{};
  int idx = 0;
  for (int l = 0; l < 5; l++) {
    int n = 2 * l + 1;
    for (int i = 0; i < n; i++)
      for (int j = 0; j < n; j++) {
        t.l[idx] = (unsigned char)l;
        t.i[idx] = (unsigned char)i;
        t.j[idx] = (unsigned char)j;
        idx++;
      }
  }
  return t;
}
__device__ __constant__ TabM c_tabM = make_tabM();

// Nonzero-entry table in sD order: irrep-major, row-major, col-major.
struct TabW { unsigned char l[NWRITE], i[NWRITE], j[NWRITE]; };
constexpr TabW make_tabW() {
  TabW t{};
  const int cnt[5] = {32, 16, 8, 8, 4};
  int idx = 0;
  for (int l = 0; l < 5; l++) {
    int n = 2 * l + 1;
    for (int c = 0; c < cnt[l]; c++)
      for (int i = 0; i < n; i++)
        for (int j = 0; j < n; j++) {
          t.l[idx] = (unsigned char)l;
          t.i[idx] = (unsigned char)i;
          t.j[idx] = (unsigned char)j;
          idx++;
        }
  }
  return t;
}
__device__ __constant__ TabW c_tabW = make_tabW();

// Per-global-row packed info: bits[0:12)=dstart into sD, [12:20)=block col
// offset, [20:24)=n. sD order matches TabW order (rows contiguous).
struct RowTab { unsigned int v[WDIM]; };
constexpr RowTab make_rows() {
  RowTab t{};
  const int cnt[5] = {32, 16, 8, 8, 4};
  int row = 0, d = 0;
  for (int li = 0; li < 5; li++) {
    int n = 2 * li + 1;
    for (int c = 0; c < cnt[li]; c++) {
      int off = row;
      for (int i = 0; i < n; i++) {
        t.v[row] = (unsigned)(d | (off << 12) | (n << 20));
        d += n;
        row++;
      }
    }
  }
  return t;
}
__device__ __constant__ RowTab c_rows = make_rows();

// ---------------- compile-time A / AINV ----------------

constexpr double csqrt(double x) {
  if (x <= 0.0) return 0.0;
  double r = x > 1.0 ? x : 1.0;
  for (int i = 0; i < 32; i++) r = 0.5 * (r + x / r);
  return r;
}

constexpr double rnd_double_c(unsigned long long x) {
  x += 0x9E3779B97F4A7C15ull;
  x = (x ^ (x >> 30)) * 0xBF58476D1CE4E5B9ull;
  x = (x ^ (x >> 27)) * 0x94D049BB133111EBull;
  x ^= x >> 31;
  return (double)(x >> 11) * (1.0 / 4503599627370496.0) - 1.0;
}

// Real SH (reference convention, CS phase inside P). Nf[m+l] holds the
// normalization incl. the sqrt(2) factor for m != 0.
constexpr void sh_eval_c(int l, const double* p, double* outv, const double* Nf) {
  const double x = p[0], y = p[1], z = p[2];
  const double rho2 = x * x + y * y;
  double c1 = 1.0, s1 = 0.0;
  if (rho2 > 1e-300) {
    double ir = 1.0 / csqrt(rho2);
    c1 = x * ir; s1 = y * ir;
  }
  double cm[5] = {1.0, 0, 0, 0, 0};
  double sm[5] = {0, 0, 0, 0, 0};
  for (int m = 1; m <= l; m++) {
    cm[m] = cm[m - 1] * c1 - sm[m - 1] * s1;
    sm[m] = sm[m - 1] * c1 + cm[m - 1] * s1;
  }
  double t = 1.0 - z * z; if (t < 0.0) t = 0.0;
  const double somx2 = csqrt(t);
  double P[5] = {};
  for (int m = 0; m <= l; m++) {
    double pmm = 1.0;
    if (m > 0) {
      double f = 1.0;
      for (int k = 0; k < m; k++) { pmm = -pmm * f * somx2; f += 2.0; }
    }
    if (l == m) { P[m] = pmm; continue; }
    double pmmp1 = z * (2 * m + 1) * pmm;
    if (l == m + 1) { P[m] = pmmp1; continue; }
    for (int ll = m + 2; ll <= l; ll++) {
      double pll = ((2 * ll - 1) * z * pmmp1 - (ll + m - 1) * pmm) / (double)(ll - m);
      pmm = pmmp1; pmmp1 = pll;
    }
    P[m] = pmmp1;
  }
  for (int m = -l; m <= l; m++) {
    int am = m < 0 ? -m : m;
    double v = (m == 0) ? Nf[l] * P[0]
             : (m > 0)  ? Nf[m + l] * P[am] * cm[am]
                        : Nf[m + l] * P[am] * sm[am];
    outv[m + l] = v;
  }
}

struct AData { float A[NBLK]; float AINV[NBLK]; };
constexpr AData make_A() {
  AData o{};
  const int moff[5] = {0, 1, 10, 35, 84};
  const double fact[9] = {1, 1, 2, 6, 24, 120, 720, 5040, 40320};
  const double four_pi = 4.0 * 3.14159265358979323846;
  for (int l = 0; l < 5; l++) {
    const int n = 2 * l + 1;
    double Nf[9] = {};
    for (int m = -l; m <= l; m++) {
      int am = m < 0 ? -m : m;
      double N = csqrt((2 * l + 1) / four_pi * fact[l - am] / fact[l + am]);
      Nf[m + l] = (m == 0) ? N : N * csqrt(2.0);
    }
    double Y[48][9] = {};
    double Yr[48][9] = {};
    for (int s = 0; s < 48; s++) {
      unsigned long long base = ((unsigned long long)l * 1024ull + (unsigned long long)s) * 4ull + 1ull;
      double p[3] = {};
      double nrm2 = 0.0;
      for (int c = 0; c < 3; c++) { p[c] = rnd_double_c(base + (unsigned long long)c); nrm2 += p[c] * p[c]; }
      if (nrm2 < 1e-12) { p[0] = 1.0; p[1] = 0.5; p[2] = 0.25; nrm2 = 1.3125; }
      double invn = 1.0 / csqrt(nrm2);
      p[0] *= invn; p[1] *= invn; p[2] *= invn;
      double q[3] = { p[0], p[2], -p[1] }; // _RX: (x,y,z) -> (x,z,-y)
      sh_eval_c(l, p, Y[s], Nf);
      sh_eval_c(l, q, Yr[s], Nf);
    }
    // Augmented normal equations [G | C], 9x18, identity padding.
    double G[9][18] = {};
    for (int r = 0; r < 9; r++)
      for (int c = 0; c < 18; c++) {
        double v = 0.0;
        if (c < 9) {
          if (r < n && c < n) { for (int s = 0; s < 48; s++) v += Y[s][r] * Y[s][c]; }
          else v = (r == c) ? 1.0 : 0.0;
        } else {
          int cc = c - 9;
          if (r < n && cc < n) { for (int s = 0; s < 48; s++) v += Y[s][r] * Yr[s][cc]; }
        }
        G[r][c] = v;
      }
    // Gauss-Jordan (SPD + identity padding; no pivoting needed).
    for (int k = 0; k < 9; k++) {
      double ip = 1.0 / G[k][k];
      for (int c = 0; c < 18; c++) G[k][c] *= ip;
      for (int r = 0; r < 9; r++)
        if (r != k) {
          double f = G[r][k];
          for (int c = 0; c < 18; c++) G[r][c] -= f * G[k][c];
        }
    }
    // X = right half solves Y@X ~= Yr ; A = X^T ; AINV = A^T = X.
    for (int i = 0; i < n; i++)
      for (int j = 0; j < n; j++) {
        o.A[moff[l] + i * n + j]    = (float)G[j][9 + i];
        o.AINV[moff[l] + i * n + j] = (float)G[i][9 + j];
      }
  }
  return o;
}
__device__ __constant__ AData c_A = make_A();

// One block per batch element. Stages all 1092 nonzeros in LDS, then writes
// the whole 212x212 slice in one float4 streaming pass (each byte once).
__global__ __launch_bounds__(256) void wigner_main(const float* __restrict__ alpha,
                                                   const float* __restrict__ beta,
                                                   const float* __restrict__ gamma,
                                                   float* __restrict__ out) {
  const int b = blockIdx.x;
  const int tid = threadIdx.x;
  const float a = alpha[b];
  const float be = beta[b];
  const float g = gamma[b];

  __shared__ float sA[330]; // A then AINV (contiguous in c_A)
  __shared__ float sT[NBLK];
  __shared__ float sM[NBLK];
  __shared__ float sD[NWRITE];
  __shared__ unsigned int sRow[WDIM];

  {
    const float* cf = (const float*)&c_A;
    for (int e = tid; e < 330; e += 256) sA[e] = cf[e];
  }
  if (tid < WDIM) sRow[tid] = c_rows.v[tid];
  __syncthreads();

  // T = Zbeta @ AINV  (Z row i: cos(m_i b) at i, -sin(m_i b) at n-1-i)
  for (int e = tid; e < NBLK; e += 256) {
    int l = c_tabM.l[e], i = c_tabM.i[e], j = c_tabM.j[e];
    int n = 2 * l + 1, moff = c_moff[l];
    int i2 = n - 1 - i;
    float mi = (float)(i - l);
    float sb, cb;
    __sincosf(mi * be, &sb, &cb);
    sT[e] = cb * sA[165 + moff + i * n + j] - sb * sA[165 + moff + i2 * n + j];
  }
  __syncthreads();

  // M = A @ T
  for (int e = tid; e < NBLK; e += 256) {
    int l = c_tabM.l[e], i = c_tabM.i[e], j = c_tabM.j[e];
    int n = 2 * l + 1, moff = c_moff[l];
    float acc = 0.f;
    for (int k = 0; k < n; k++) acc += sA[moff + i * n + k] * sT[moff + k * n + j];
    sM[e] = acc;
  }
  __syncthreads();

  // sD[t] = cos(mi*a)*(M[i,j]cg + M[i,j']sg) - sin(mi*a)*(M[i',j]cg + M[i',j']sg)
  for (int t = tid; t < NWRITE; t += 256) {
    int l = c_tabW.l[t], i = c_tabW.i[t], j = c_tabW.j[t];
    int n = 2 * l + 1, moff = c_moff[l];
    int i2 = n - 1 - i, j2 = n - 1 - j;
    float mi = (float)(i - l), mj = (float)(j - l);
    float sa, ca, sg, cg;
    __sincosf(mi * a, &sa, &ca);
    __sincosf(mj * g, &sg, &cg);
    float r0 = sM[moff + i * n + j] * cg + sM[moff + i * n + j2] * sg;
    float r1 = sM[moff + i2 * n + j] * cg + sM[moff + i2 * n + j2] * sg;
    sD[t] = ca * r0 - sa * r1;
  }
  __syncthreads();

  // Streaming pass: 11236 float4s, each byte written exactly once.
  vfloat4* __restrict__ oz = (vfloat4*)(out + (size_t)b * SLICE);
  #pragma unroll 2
  for (int e = tid; e < SLICE4; e += 256) {
    int r = e / 53;              // magic-mul division
    int c0 = (e - r * 53) * 4;   // starting global col of this float4
    unsigned info = sRow[r];
    int dstart = info & 0xFFF;
    int off = (info >> 12) & 0xFF;
    int n = (info >> 20) & 0xF;
    vfloat4 v = (vfloat4)(0.f);
    int i0 = c0 - off;
    #pragma unroll
    for (int q = 0; q < 4; q++) {
      int idx = i0 + q;
      if ((unsigned)idx < (unsigned)n) v[q] = sD[dstart + idx];
    }
    oz[e] = v;
  }
}

extern "C" void kernel_launch(void* const* d_in, const int* in_sizes, int n_in,
                              void* d_out, int out_size, void* d_ws, size_t ws_size,
                              hipStream_t stream) {
  const float* alpha = (const float*)d_in[0];
  const float* beta  = (const float*)d_in[1];
  const float* gamma = (const float*)d_in[2];
  float* out = (float*)d_out;
  const int B = in_sizes[0];

  // Single kernel: zeros + diagonal blocks, exactly 368 MB of HBM writes.
  // A/AINV are compile-time constants (no setup kernel).
  wigner_main<<<B, 256, 0, stream>>>(alpha, beta, gamma, out);
}